// Round 19
// baseline (633.234 us; speedup 1.0000x reference)
//
#include <hip/hip_runtime.h>
#include <hip/hip_bf16.h>
#include <math.h>

#define B_   8
#define T_   1024
#define K_   76
#define KP_  96      // padded model dim (3 x 32)
#define H_   8
#define D_   6
#define C_   2
#define HK_  608     // H*K (packed att layout)
#define QKLD_ 640    // q/k row stride: 8 heads x 80
#define FF_  304     // 4*K
#define FFP_ 320     // padded FF
#define EK_  320     // embed GEMM K (291 used + 1.0 col + pad)
#define BT_  8192
#define EPS_ 1e-5f
#define SCL2_ (0.11470786693528088f * 1.4426950408889634f)  // 1/sqrt(76)*log2(e)

typedef unsigned short u16;
typedef unsigned int u32;
typedef short bf16x8 __attribute__((ext_vector_type(8)));
typedef float f32x4 __attribute__((ext_vector_type(4)));

__device__ __forceinline__ u16 f2b(float f) {
  __hip_bfloat16 h = __float2bfloat16(f);
  return *reinterpret_cast<u16*>(&h);
}
__device__ __forceinline__ float b2f(u16 u) {
  __hip_bfloat16 h = *reinterpret_cast<__hip_bfloat16*>(&u);
  return __bfloat162float(h);
}
__device__ __forceinline__ u32 pack2(float a, float b) {
  __hip_bfloat162 t = __float22bfloat162_rn(make_float2(a, b));
  return *reinterpret_cast<u32*>(&t);
}

// =================== merged prologue: wconv (bid<1368) | wembed | pack ===========
#define PER_L_ 304128ULL
__global__ __launch_bounds__(256) void prep_kernel(
    const float* __restrict__ Wq, const float* __restrict__ Wk, const float* __restrict__ Wv,
    const float* __restrict__ Wu, const float* __restrict__ W1, const float* __restrict__ W2,
    u16* __restrict__ WT,
    const float* __restrict__ W_hp, const float* __restrict__ b_hp,
    const float* __restrict__ W_lm, const float* __restrict__ b_lm,
    const float* __restrict__ W_el, const float* __restrict__ b_el,
    const float* __restrict__ W_au, const float* __restrict__ b_au,
    u16* __restrict__ WE,
    const float* __restrict__ v, const float* __restrict__ x,
    const float* __restrict__ y, const float* __restrict__ z,
    u16* __restrict__ xin) {
  __shared__ float Ls[32][65];
  const int bid = blockIdx.x;
  if (bid < 1368) {
    int tile = bid % 38, zz = bid / 38;
    int d = zz / 6, wt = zz % 6;
    const float* in; int Kd, Nsrc, Nalloc, Kp; u16* out;
    size_t lb = (size_t)d * PER_L_;
    switch (wt) {
      case 0: in = Wq + (size_t)d*K_*HK_; Kd=K_;  Nsrc=HK_; Nalloc=640; Kp=KP_;  out = WT + lb;          break;
      case 1: in = Wk + (size_t)d*K_*HK_; Kd=K_;  Nsrc=HK_; Nalloc=640; Kp=KP_;  out = WT + lb + 61440;  break;
      case 2: in = Wv + (size_t)d*K_*HK_; Kd=K_;  Nsrc=HK_; Nalloc=640; Kp=KP_;  out = WT + lb + 122880; break;
      case 3: in = Wu + (size_t)d*HK_*K_; Kd=HK_; Nsrc=K_;  Nalloc=96;  Kp=HK_;  out = WT + lb + 184320; break;
      case 4: in = W1 + (size_t)d*K_*FF_; Kd=K_;  Nsrc=FF_; Nalloc=320; Kp=KP_;  out = WT + lb + 242688; break;
      default:in = W2 + (size_t)d*FF_*K_; Kd=FF_; Nsrc=K_;  Nalloc=96;  Kp=FFP_; out = WT + lb + 273408; break;
    }
    int tiles_k = Kp / 32;
    int tiles_n = (Nalloc + 63) / 64;
    if (tile >= tiles_k * tiles_n) return;
    int tn = tile / tiles_k, tk = tile % tiles_k;
    int n0 = tn * 64, k0 = tk * 32;
    for (int i = threadIdx.x; i < 2048; i += 256) {
      int kk = i >> 6, nn = i & 63;
      int gk = k0 + kk, gn = n0 + nn;
      int srccol = gn;
      if (wt < 3) {
        int hh8 = gn / 80, ft = gn - hh8 * 80;
        srccol = (ft < 76) ? (hh8 * 76 + ft) : -1;
      }
      Ls[kk][nn] = (gk < Kd && srccol >= 0 && srccol < Nsrc) ? in[(size_t)gk * Nsrc + srccol] : 0.f;
    }
    __syncthreads();
    for (int i = threadIdx.x; i < 2048; i += 256) {
      int nn = i >> 5, kk = i & 31;
      int gn = n0 + nn;
      if (gn < Nalloc) out[(size_t)gn * Kp + k0 + kk] = f2b(Ls[kk][nn]);
    }
  } else if (bid < 1488) {
    int idx = (bid - 1368) * 256 + threadIdx.x;
    if (idx >= 96 * EK_) return;
    int n = idx / EK_, kk = idx % EK_;
    float val = 0.f;
    if (n < 76) {
      if (kk < 6) { if (n < 6) val = W_hp[kk * 6 + n]; }
      else if (kk < 143) { int i = kk - 6; if (n >= 6 && n < 36) val = W_lm[i * 30 + (n - 6)]; }
      else if (kk < 256) { int i = kk - 143; if (n >= 36 && n < 66) val = W_el[i * 30 + (n - 36)]; }
      else if (kk < 291) { int i = kk - 256; if (n >= 66) val = W_au[i * 10 + (n - 66)]; }
      else if (kk == 291) {
        val = (n < 6) ? b_hp[n] : (n < 36) ? b_lm[n - 6] : (n < 66) ? b_el[n - 36] : b_au[n - 66];
      }
    }
    WE[idx] = f2b(val);
  } else {
    int idx = (bid - 1488) * 256 + threadIdx.x;
    if (idx >= BT_ * (EK_ / 2)) return;
    int bt = idx / (EK_ / 2), dc = idx % (EK_ / 2);
    int c0 = dc * 2;
    auto fetch = [&](int c) -> float {
      if (c < 6) return v[bt * 6 + c];
      if (c < 143) return x[bt * 137 + c - 6];
      if (c < 256) return y[bt * 113 + c - 143];
      if (c < 291) return z[bt * 35 + c - 256];
      if (c == 291) return 1.0f;
      return 0.f;
    };
    ((u32*)xin)[idx] = pack2(fetch(c0), fetch(c0 + 1));
  }
}

// =================== MFMA GEMM (LDS-staged B, prefetch) — embed + QKV ====
template<int RT, int CT, int KSTEPS, int RELU, int TPB>
__global__ __launch_bounds__(TPB) void gemm_kernel(
    const u16* __restrict__ A, int lda,
    const u16* __restrict__ Wt, int ldw, unsigned long long wstride,
    const float* __restrict__ bias,
    u16* __restrict__ Cc, int ldc, int N,
    int ksplit, int klen, unsigned long long osplit,
    float cs,
    u16* __restrict__ vbt,
    const float* __restrict__ pos) {
  __shared__ u16 Bs[CT * 16 * 56];
  const int tid = threadIdx.x;
  const int w = tid >> 6, lane = tid & 63;
  const int r = lane & 15, g = lane >> 4;
  const int n0 = blockIdx.x * CT * 16;
  const int m0 = blockIdx.y * (TPB / 64) * 16 * RT;
  const int z = blockIdx.z;
  const int k0 = z * ksplit;
  const int kend = k0 + klen;
  const u16* Wz = Wt + (size_t)z * wstride;
  const float* bias_eff = (z == 0) ? bias : nullptr;
  const float csz = (z == 0) ? cs : 1.f;
  u16* Cz = Cc + (size_t)z * osplit;
  constexpr int NB = (CT * 64 + TPB - 1) / TPB;

  const f32x4 fz = {0.f, 0.f, 0.f, 0.f};
  f32x4 acc[RT][CT];
  #pragma unroll
  for (int rt = 0; rt < RT; rt++)
    #pragma unroll
    for (int ct = 0; ct < CT; ct++) acc[rt][ct] = fz;

  bf16x8 a_all[RT][KSTEPS];
  #pragma unroll
  for (int rt = 0; rt < RT; rt++) {
    const u16* arow = A + (size_t)(m0 + (w * RT + rt) * 16 + r) * lda;
    #pragma unroll
    for (int ks = 0; ks < KSTEPS; ks++) {
      int kA = k0 + ks * 32 + g * 8;
      if (kA < kend) a_all[rt][ks] = *(const bf16x8*)(arow + kA);
      else a_all[rt][ks] = bf16x8{0, 0, 0, 0, 0, 0, 0, 0};
    }
  }

  uint4 bpre[NB];
  auto loadB = [&](int ks) {
    int kk = k0 + ks * 32;
    #pragma unroll
    for (int i0 = 0; i0 < NB; i0++) {
      int idx = tid + i0 * TPB;
      bpre[i0] = make_uint4(0, 0, 0, 0);
      if (idx < CT * 64) {
        int nn = idx >> 2, kc = idx & 3;
        if (kk + kc * 8 < kend)
          bpre[i0] = *(const uint4*)(Wz + (size_t)(n0 + nn) * ldw + kk + kc * 8);
      }
    }
  };
  loadB(0);

  for (int ks = 0; ks < KSTEPS; ks++) {
    __syncthreads();
    #pragma unroll
    for (int i0 = 0; i0 < NB; i0++) {
      int idx = tid + i0 * TPB;
      if (idx < CT * 64) {
        int nn = idx >> 2, kc = idx & 3;
        *(uint4*)&Bs[nn * 56 + (((kc ^ (nn & 3)) << 3))] = bpre[i0];
      }
    }
    __syncthreads();
    if (ks + 1 < KSTEPS) loadB(ks + 1);
    #pragma unroll
    for (int ct = 0; ct < CT; ct++) {
      bf16x8 bb = *(const bf16x8*)&Bs[(ct * 16 + r) * 56 + (((g ^ (r & 3)) << 3))];
      #pragma unroll
      for (int rt = 0; rt < RT; rt++)
        acc[rt][ct] = __builtin_amdgcn_mfma_f32_16x16x32_bf16(a_all[rt][ks], bb, acc[rt][ct], 0, 0, 0);
    }
  }

  if (vbt && z == 2) {
    #pragma unroll
    for (int rt = 0; rt < RT; rt++) {
      #pragma unroll
      for (int ct = 0; ct < CT; ct++) {
        int feat = ct * 16 + r;
        int token = m0 + (w * RT + rt) * 16 + g * 4;
        int bb_ = token >> 10, tt = token & 1023;
        ushort4 pk;
        if (feat < 76) {
          pk.x = f2b(acc[rt][ct][0]); pk.y = f2b(acc[rt][ct][1]);
          pk.z = f2b(acc[rt][ct][2]); pk.w = f2b(acc[rt][ct][3]);
        } else {
          pk = make_ushort4(0, 0, 0, 0);
        }
        *(ushort4*)(vbt + (((size_t)(bb_ * 8 + blockIdx.x) * 80 + feat) << 10) + tt) = pk;
      }
    }
  } else {
    #pragma unroll
    for (int rt = 0; rt < RT; rt++) {
      #pragma unroll
      for (int ct = 0; ct < CT; ct++) {
        int col = n0 + ct * 16 + r;
        if (col < ldc) {
          #pragma unroll
          for (int reg = 0; reg < 4; reg++) {
            int row = m0 + (w * RT + rt) * 16 + g * 4 + reg;
            float val = acc[rt][ct][reg] * csz;
            if (bias_eff && col < N) val += bias_eff[col];
            if (pos && col < N) val += pos[(row & (T_ - 1)) * K_ + col];
            if (RELU) val = fmaxf(val, 0.f);
            Cz[(size_t)row * ldc + col] = f2b(val);
          }
        }
      }
    }
  }
}

// =================== fused FFN: 8 rows/wave, grid 1024 (4 waves/CU); rows 8..15 redundant ===
__global__ __launch_bounds__(64) void ffn_kernel(
    const u16* __restrict__ att, const u16* __restrict__ WuT, const float* __restrict__ bu,
    const u16* __restrict__ hres, const float* __restrict__ l1s, const float* __restrict__ l1b,
    const u16* __restrict__ W1T, const float* __restrict__ b1,
    const u16* __restrict__ W2T, const float* __restrict__ b2,
    const float* __restrict__ l2s, const float* __restrict__ l2b,
    u16* __restrict__ hout,
    const float* __restrict__ Wout, const float* __restrict__ bout,
    float* __restrict__ outp) {
  __shared__ u16 Bs[6 * 16 * 56];
  __shared__ u16 h1s[16 * 104];
  __shared__ u16 ffs[16 * 328];
  const int lane = threadIdx.x & 63;
  const int r = lane & 15, g = lane >> 4;
  const int m0 = blockIdx.x * 8;     // 8 owned rows; rows 8..15 computed (next block's) but not stored
  const f32x4 fz = {0.f, 0.f, 0.f, 0.f};

  // clamped row helper (last block's rows 8..15 would be OOB)
  auto rowclamp = [&](int t) { return (t < BT_) ? t : (BT_ - 1); };

  u16 resv[4][6];
  #pragma unroll
  for (int reg = 0; reg < 4; reg++)
    #pragma unroll
    for (int ct = 0; ct < 6; ct++)
      resv[reg][ct] = hres[(size_t)rowclamp(m0 + g * 4 + reg) * KP_ + ct * 16 + r];

  // ---- stage 1: u = att @ WuT ----
  bf16x8 a1[19];
  {
    const u16* arow = att + (size_t)rowclamp(m0 + r) * HK_;
    #pragma unroll
    for (int ks = 0; ks < 19; ks++) a1[ks] = *(const bf16x8*)(arow + ks * 32 + g * 8);
  }
  f32x4 acc1[6];
  #pragma unroll
  for (int ct = 0; ct < 6; ct++) acc1[ct] = fz;
  {
    uint4 bpre[6];
    auto loadB1 = [&](int ks) {
      #pragma unroll
      for (int i0 = 0; i0 < 6; i0++) {
        int idx = lane + i0 * 64;
        int nn = idx >> 2, kc = idx & 3;
        bpre[i0] = *(const uint4*)(WuT + (size_t)nn * HK_ + ks * 32 + kc * 8);
      }
    };
    loadB1(0);
    for (int ks = 0; ks < 19; ks++) {
      #pragma unroll
      for (int i0 = 0; i0 < 6; i0++) {
        int idx = lane + i0 * 64;
        int nn = idx >> 2, kc = idx & 3;
        *(uint4*)&Bs[nn * 56 + ((kc ^ (nn & 3)) << 3)] = bpre[i0];
      }
      if (ks + 1 < 19) loadB1(ks + 1);
      #pragma unroll
      for (int ct = 0; ct < 6; ct++) {
        bf16x8 bb = *(const bf16x8*)&Bs[(ct * 16 + r) * 56 + ((g ^ (r & 3)) << 3)];
        acc1[ct] = __builtin_amdgcn_mfma_f32_16x16x32_bf16(a1[ks], bb, acc1[ct], 0, 0, 0);
      }
    }
  }
  #pragma unroll
  for (int reg = 0; reg < 4; reg++) {
    float vals[6];
    float s = 0.f, s2 = 0.f;
    #pragma unroll
    for (int ct = 0; ct < 6; ct++) {
      int col = ct * 16 + r;
      float val = 0.f;
      if (col < K_) {
        val = acc1[ct][reg] + bu[col] + b2f(resv[reg][ct]);
        s += val; s2 += val * val;
      }
      vals[ct] = val;
    }
    #pragma unroll
    for (int m = 1; m < 16; m <<= 1) { s += __shfl_xor(s, m); s2 += __shfl_xor(s2, m); }
    float mu = s * (1.f / 76.f);
    float rstd = rsqrtf(s2 * (1.f / 76.f) - mu * mu + EPS_);
    #pragma unroll
    for (int ct = 0; ct < 6; ct++) {
      int col = ct * 16 + r;
      u16 ov = 0;
      if (col < K_) ov = f2b((vals[ct] - mu) * rstd * l1s[col] + l1b[col]);
      h1s[(g * 4 + reg) * 104 + col] = ov;
    }
  }

  // ---- stage 2: ff = relu(h1 @ W1T + b1) ----
  bf16x8 a2[3];
  #pragma unroll
  for (int ks = 0; ks < 3; ks++)
    a2[ks] = *(const bf16x8*)&h1s[r * 104 + ks * 32 + g * 8];
  f32x4 acc2[20];
  #pragma unroll
  for (int ct = 0; ct < 20; ct++) acc2[ct] = fz;
  #pragma unroll
  for (int ks = 0; ks < 3; ks++) {
    bf16x8 bb[20];
    #pragma unroll
    for (int ct = 0; ct < 20; ct++)
      bb[ct] = *(const bf16x8*)(W1T + (size_t)(ct * 16 + r) * KP_ + ks * 32 + g * 8);
    #pragma unroll
    for (int ct = 0; ct < 20; ct++)
      acc2[ct] = __builtin_amdgcn_mfma_f32_16x16x32_bf16(a2[ks], bb[ct], acc2[ct], 0, 0, 0);
  }
  #pragma unroll
  for (int reg = 0; reg < 4; reg++)
    #pragma unroll
    for (int ct = 0; ct < 20; ct++) {
      int col = ct * 16 + r;
      float val = acc2[ct][reg] + ((col < FF_) ? b1[col] : 0.f);
      ffs[(g * 4 + reg) * 328 + col] = f2b(fmaxf(val, 0.f));
    }

  // ---- stage 3: u2 = ff @ W2T + b2 + h1 residual + LN2 (+out proj); store rows < 8 only ----
  bf16x8 a3[10];
  #pragma unroll
  for (int ks = 0; ks < 10; ks++)
    a3[ks] = *(const bf16x8*)&ffs[r * 328 + ks * 32 + g * 8];
  f32x4 acc3[6];
  #pragma unroll
  for (int ct = 0; ct < 6; ct++) acc3[ct] = fz;
  {
    uint4 bpre[6];
    auto loadB3 = [&](int ks) {
      #pragma unroll
      for (int i0 = 0; i0 < 6; i0++) {
        int idx = lane + i0 * 64;
        int nn = idx >> 2, kc = idx & 3;
        bpre[i0] = *(const uint4*)(W2T + (size_t)nn * FFP_ + ks * 32 + kc * 8);
      }
    };
    loadB3(0);
    for (int ks = 0; ks < 10; ks++) {
      #pragma unroll
      for (int i0 = 0; i0 < 6; i0++) {
        int idx = lane + i0 * 64;
        int nn = idx >> 2, kc = idx & 3;
        *(uint4*)&Bs[nn * 56 + ((kc ^ (nn & 3)) << 3)] = bpre[i0];
      }
      if (ks + 1 < 10) loadB3(ks + 1);
      #pragma unroll
      for (int ct = 0; ct < 6; ct++) {
        bf16x8 bb = *(const bf16x8*)&Bs[(ct * 16 + r) * 56 + ((g ^ (r & 3)) << 3)];
        acc3[ct] = __builtin_amdgcn_mfma_f32_16x16x32_bf16(a3[ks], bb, acc3[ct], 0, 0, 0);
      }
    }
  }
  #pragma unroll
  for (int reg = 0; reg < 4; reg++) {
    int tr = g * 4 + reg;              // token row within the 16-row MFMA tile
    if (tr >= 8) continue;             // rows 8..15 belong to the next block
    float vals[6];
    float s = 0.f, s2 = 0.f;
    #pragma unroll
    for (int ct = 0; ct < 6; ct++) {
      int col = ct * 16 + r;
      float val = 0.f;
      if (col < K_) {
        val = acc3[ct][reg] + b2[col] + b2f(h1s[tr * 104 + col]);
        s += val; s2 += val * val;
      }
      vals[ct] = val;
    }
    #pragma unroll
    for (int m = 1; m < 16; m <<= 1) { s += __shfl_xor(s, m); s2 += __shfl_xor(s2, m); }
    float mu = s * (1.f / 76.f);
    float rstd = rsqrtf(s2 * (1.f / 76.f) - mu * mu + EPS_);
    u16* outr = hout + (size_t)(m0 + tr) * KP_;
    float p0 = 0.f, p1 = 0.f;
    #pragma unroll
    for (int ct = 0; ct < 6; ct++) {
      int col = ct * 16 + r;
      u16 ov = 0;
      if (col < K_) {
        float vln = (vals[ct] - mu) * rstd * l2s[col] + l2b[col];
        ov = f2b(vln);
        if (outp) {
          p0 += vln * Wout[col * 2];
          p1 += vln * Wout[col * 2 + 1];
        }
      }
      outr[col] = ov;
    }
    if (outp) {
      #pragma unroll
      for (int m = 1; m < 16; m <<= 1) { p0 += __shfl_xor(p0, m); p1 += __shfl_xor(p1, m); }
      if (r == 0) {
        int row = m0 + tr;
        outp[row * 2] = p0 + bout[0];
        outp[row * 2 + 1] = p1 + bout[1];
      }
    }
  }
}

// =================== flash attention: 4-wave rt=2, single-buffered K/V (proven) ===
__global__ __launch_bounds__(256, 3) void attn_kernel(const u16* __restrict__ q,
                                                      const u16* __restrict__ k,
                                                      const u16* __restrict__ vbt,
                                                      u16* __restrict__ att) {
  __shared__ u16 Ks[64 * 104];   // 52 dw stride (13 odd -> conflict-free b128)
  __shared__ u16 Vs[80 * 72];    // 36 dw stride (9 odd)
  __shared__ u32 Psw[128 * 36];  // wave-private rows
  const int bid = blockIdx.x;
  const int hh = bid & 7, b = (bid >> 3) & 7, qt = bid >> 6;
  const int tid = threadIdx.x;
  const int w = tid >> 6, lane = tid & 63;
  const int r = lane & 15, g = lane >> 4;
  const int qbase = b * T_ + qt * 128;

  bf16x8 aq[2][3];
  #pragma unroll
  for (int rt = 0; rt < 2; rt++) {
    const u16* qsrc = q + (size_t)(qbase + w * 32 + rt * 16 + r) * QKLD_ + hh * 80;
    #pragma unroll
    for (int ks = 0; ks < 3; ks++) {
      int e0 = ks * 32 + g * 8;
      aq[rt][ks] = (e0 < 80) ? *(const bf16x8*)(qsrc + e0) : bf16x8{0, 0, 0, 0, 0, 0, 0, 0};
    }
  }

  const int krow = tid >> 2, kq4 = tid & 3;
  uint4 kpre[3], vpre[3];
  auto stage_load = [&](int kt) {
    const int kb = b * T_ + kt * 64;
    const u16* ksrc = k + (size_t)(kb + krow) * QKLD_ + hh * 80;
    #pragma unroll
    for (int i = 0; i < 3; i++) {
      int c = kq4 + 4 * i;
      kpre[i] = (c < 10) ? *(const uint4*)(ksrc + c * 8) : make_uint4(0, 0, 0, 0);
    }
    const u16* vsrc = vbt + (((size_t)(b * 8 + hh) * 80) << 10) + kt * 64;
    #pragma unroll
    for (int p = 0; p < 3; p++) {
      int idx = tid + p * 256;
      vpre[p] = (idx < 640) ? *(const uint4*)(vsrc + ((size_t)(idx >> 3) << 10) + (idx & 7) * 8)
                            : make_uint4(0, 0, 0, 0);
    }
  };
  auto stage_write = [&]() {
    #pragma unroll
    for (int i = 0; i < 3; i++) {
      int c = kq4 + 4 * i;
      *(uint4*)&Ks[krow * 104 + c * 8] = kpre[i];
    }
    #pragma unroll
    for (int p = 0; p < 3; p++) {
      int idx = tid + p * 256;
      if (idx < 640)
        *(uint4*)&Vs[(idx >> 3) * 72 + (idx & 7) * 8] = vpre[p];
    }
  };

  u32* Pw = Psw + w * 32 * 36;

  const f32x4 fz = {0.f, 0.f, 0.f, 0.f};
  f32x4 o[2][5];
  float ls[2] = {0.f, 0.f};
  #pragma unroll
  for (int rt = 0; rt < 2; rt++)
    #pragma unroll
    for (int i = 0; i < 5; i++) o[rt][i] = fz;

  stage_load(0);

  for (int kt = 0; kt < 16; kt++) {
    __syncthreads();
    stage_write();
    __syncthreads();
    if (kt < 15) stage_load(kt + 1);

    f32x4 st[2][4];
    #pragma unroll
    for (int ct = 0; ct < 4; ct++) { st[0][ct] = fz; st[1][ct] = fz; }
    __builtin_amdgcn_s_setprio(1);
    #pragma unroll
    for (int ct = 0; ct < 4; ct++) {
      #pragma unroll
      for (int ks = 0; ks < 3; ks++) {
        bf16x8 ak = *(const bf16x8*)&Ks[(ct * 16 + r) * 104 + ks * 32 + g * 8];
        st[0][ct] = __builtin_amdgcn_mfma_f32_16x16x32_bf16(ak, aq[0][ks], st[0][ct], 0, 0, 0);
        st[1][ct] = __builtin_amdgcn_mfma_f32_16x16x32_bf16(ak, aq[1][ks], st[1][ct], 0, 0, 0);
      }
    }
    __builtin_amdgcn_s_setprio(0);

    #pragma unroll
    for (int rt = 0; rt < 2; rt++) {
      float rs = 0.f;
      u32 pk[8];
      #pragma unroll
      for (int ct = 0; ct < 4; ct++) {
        float p0 = exp2f(st[rt][ct][0]), p1 = exp2f(st[rt][ct][1]);
        float p2 = exp2f(st[rt][ct][2]), p3 = exp2f(st[rt][ct][3]);
        rs += (p0 + p1) + (p2 + p3);
        pk[ct * 2] = pack2(p0, p1);
        pk[ct * 2 + 1] = pack2(p2, p3);
      }
      ls[rt] += rs;
      u32* pw = Pw + (rt * 16 + r) * 36;
      #pragma unroll
      for (int ct = 0; ct < 4; ct++)
        *(uint2*)(pw + ct * 8 + g * 2) = make_uint2(pk[ct * 2], pk[ct * 2 + 1]);
    }

    bf16x8 pa[2][2];
    #pragma unroll
    for (int rt = 0; rt < 2; rt++) {
      const u32* pr = Pw + (rt * 16 + r) * 36;
      #pragma unroll
      for (int ks = 0; ks < 2; ks++) {
        uint4 t = *(const uint4*)(pr + ks * 16 + g * 4);
        pa[rt][ks] = *reinterpret_cast<bf16x8*>(&t);
      }
    }
    __builtin_amdgcn_s_setprio(1);
    #pragma unroll
    for (int ks = 0; ks < 2; ks++) {
      #pragma unroll
      for (int c5 = 0; c5 < 5; c5++) {
        bf16x8 av = *(const bf16x8*)&Vs[(c5 * 16 + r) * 72 + ks * 32 + g * 8];
        #pragma unroll
        for (int rt = 0; rt < 2; rt++)
          o[rt][c5] = __builtin_amdgcn_mfma_f32_16x16x32_bf16(av, pa[rt][ks], o[rt][c5], 0, 0, 0);
      }
    }
    __builtin_amdgcn_s_setprio(0);
  }

  #pragma unroll
  for (int rt = 0; rt < 2; rt++) {
    ls[rt] += __shfl_xor(ls[rt], 16);
    ls[rt] += __shfl_xor(ls[rt], 32);
    float inv = 1.f / ls[rt];
    int token = qbase + w * 32 + rt * 16 + r;
    #pragma unroll
    for (int c5 = 0; c5 < 5; c5++) {
      if (c5 == 4 && g == 3) continue;
      ushort4 pk4;
      pk4.x = f2b(o[rt][c5][0] * inv);
      pk4.y = f2b(o[rt][c5][1] * inv);
      pk4.z = f2b(o[rt][c5][2] * inv);
      pk4.w = f2b(o[rt][c5][3] * inv);
      *(ushort4*)&att[(size_t)token * HK_ + hh * 76 + c5 * 16 + g * 4] = pk4;
    }
  }
}

extern "C" void kernel_launch(void* const* d_in, const int* in_sizes, int n_in,
                              void* d_out, int out_size, void* d_ws, size_t ws_size,
                              hipStream_t stream) {
  const float* v    = (const float*)d_in[0];
  const float* x    = (const float*)d_in[1];
  const float* y    = (const float*)d_in[2];
  const float* z    = (const float*)d_in[3];
  const float* W_hp = (const float*)d_in[4];
  const float* b_hp = (const float*)d_in[5];
  const float* W_lm = (const float*)d_in[6];
  const float* b_lm = (const float*)d_in[7];
  const float* W_el = (const float*)d_in[8];
  const float* b_el = (const float*)d_in[9];
  const float* W_au = (const float*)d_in[10];
  const float* b_au = (const float*)d_in[11];
  const float* pos  = (const float*)d_in[12];
  const float* Wq   = (const float*)d_in[13];
  const float* Wk   = (const float*)d_in[14];
  const float* Wv   = (const float*)d_in[15];
  const float* Wu   = (const float*)d_in[16];
  const float* bu   = (const float*)d_in[17];
  const float* ln1s = (const float*)d_in[18];
  const float* ln1b = (const float*)d_in[19];
  const float* W1   = (const float*)d_in[20];
  const float* b1   = (const float*)d_in[21];
  const float* W2   = (const float*)d_in[22];
  const float* b2   = (const float*)d_in[23];
  const float* ln2s = (const float*)d_in[24];
  const float* ln2b = (const float*)d_in[25];
  const float* Wout = (const float*)d_in[26];
  const float* bout = (const float*)d_in[27];

  u16* ws  = (u16*)d_ws;
  u16* WT  = ws;                          // 6*304128 = 1824768
  u16* WE  = WT + 1824768;                // 96*320
  u16* h   = WE + 30720;                  // 8192*96
  u16* xin = h + 786432;                  // 8192*320
  u16* qb  = xin + 2621440;               // 8192*640
  u16* kb  = qb + 5242880;                // 8192*640
  u16* vbt = kb + 5242880;                // 64*80*1024
  u16* att = vbt + 5242880;               // 8192*608

  prep_kernel<<<dim3(6608), 256, 0, stream>>>(
      Wq, Wk, Wv, Wu, W1, W2, WT,
      W_hp, b_hp, W_lm, b_lm, W_el, b_el, W_au, b_au, WE,
      v, x, y, z, xin);
  // embed GEMM: h = xin @ WE^T (+pos epilogue)
  gemm_kernel<1, 6, 10, 0, 128><<<dim3(1, 256, 1), 128, 0, stream>>>(
      xin, EK_, WE, EK_, 0ULL, nullptr, h, KP_, K_, 0, EK_, 0ULL,
      1.f, nullptr, pos);

  for (int d = 0; d < D_; d++) {
    u16* WTd = WT + (size_t)d * PER_L_;
    const float* bu_d = bu + (size_t)d * K_;
    const float* l1s  = ln1s + (size_t)d * K_;
    const float* l1b  = ln1b + (size_t)d * K_;
    const float* b1_d = b1 + (size_t)d * FF_;
    const float* b2_d = b2 + (size_t)d * K_;
    const float* l2s  = ln2s + (size_t)d * K_;
    const float* l2b  = ln2b + (size_t)d * K_;

    // QKV: z=0 -> qb (scaled by SCL2_), z=1 -> kb, z=2 -> vbt (transposed)
    gemm_kernel<2, 5, 3, 0, 256><<<dim3(8, 64, 3), 256, 0, stream>>>(
        h, KP_, WTd, KP_, 61440ULL, nullptr, qb, QKLD_, QKLD_, 0, KP_, 5242880ULL,
        SCL2_, vbt, nullptr);
    attn_kernel<<<dim3(512), 256, 0, stream>>>(qb, kb, vbt, att);
    // fused FFN, 8 rows/wave (+ final out projection on the last layer)
    ffn_kernel<<<dim3(1024), 64, 0, stream>>>(
        att, WTd + 184320, bu_d, h, l1s, l1b,
        WTd + 242688, b1_d, WTd + 273408, b2_d, l2s, l2b, h,
        Wout, bout, (d == D_ - 1) ? (float*)d_out : nullptr);
  }
}

// Round 20
// 512.627 us; speedup vs baseline: 1.2353x; 1.2353x over previous
//
#include <hip/hip_runtime.h>
#include <hip/hip_bf16.h>
#include <math.h>

#define B_   8
#define T_   1024
#define K_   76
#define KP_  96      // padded model dim (3 x 32)
#define H_   8
#define D_   6
#define C_   2
#define HK_  608     // H*K (packed att layout)
#define QKLD_ 640    // q/k row stride: 8 heads x 80
#define FF_  304     // 4*K
#define FFP_ 320     // padded FF
#define EK_  320     // embed GEMM K (291 used + 1.0 col + pad)
#define BT_  8192
#define EPS_ 1e-5f
#define SCL2_ (0.11470786693528088f * 1.4426950408889634f)  // 1/sqrt(76)*log2(e)

typedef unsigned short u16;
typedef unsigned int u32;
typedef short bf16x8 __attribute__((ext_vector_type(8)));
typedef float f32x4 __attribute__((ext_vector_type(4)));

__device__ __forceinline__ u16 f2b(float f) {
  __hip_bfloat16 h = __float2bfloat16(f);
  return *reinterpret_cast<u16*>(&h);
}
__device__ __forceinline__ float b2f(u16 u) {
  __hip_bfloat16 h = *reinterpret_cast<__hip_bfloat16*>(&u);
  return __bfloat162float(h);
}
__device__ __forceinline__ u32 pack2(float a, float b) {
  __hip_bfloat162 t = __float22bfloat162_rn(make_float2(a, b));
  return *reinterpret_cast<u32*>(&t);
}

// =================== merged prologue: wconv (bid<1368) | wembed | pack ===========
#define PER_L_ 304128ULL
__global__ __launch_bounds__(256) void prep_kernel(
    const float* __restrict__ Wq, const float* __restrict__ Wk, const float* __restrict__ Wv,
    const float* __restrict__ Wu, const float* __restrict__ W1, const float* __restrict__ W2,
    u16* __restrict__ WT,
    const float* __restrict__ W_hp, const float* __restrict__ b_hp,
    const float* __restrict__ W_lm, const float* __restrict__ b_lm,
    const float* __restrict__ W_el, const float* __restrict__ b_el,
    const float* __restrict__ W_au, const float* __restrict__ b_au,
    u16* __restrict__ WE,
    const float* __restrict__ v, const float* __restrict__ x,
    const float* __restrict__ y, const float* __restrict__ z,
    u16* __restrict__ xin) {
  __shared__ float Ls[32][65];
  const int bid = blockIdx.x;
  if (bid < 1368) {
    int tile = bid % 38, zz = bid / 38;
    int d = zz / 6, wt = zz % 6;
    const float* in; int Kd, Nsrc, Nalloc, Kp; u16* out;
    size_t lb = (size_t)d * PER_L_;
    switch (wt) {
      case 0: in = Wq + (size_t)d*K_*HK_; Kd=K_;  Nsrc=HK_; Nalloc=640; Kp=KP_;  out = WT + lb;          break;
      case 1: in = Wk + (size_t)d*K_*HK_; Kd=K_;  Nsrc=HK_; Nalloc=640; Kp=KP_;  out = WT + lb + 61440;  break;
      case 2: in = Wv + (size_t)d*K_*HK_; Kd=K_;  Nsrc=HK_; Nalloc=640; Kp=KP_;  out = WT + lb + 122880; break;
      case 3: in = Wu + (size_t)d*HK_*K_; Kd=HK_; Nsrc=K_;  Nalloc=96;  Kp=HK_;  out = WT + lb + 184320; break;
      case 4: in = W1 + (size_t)d*K_*FF_; Kd=K_;  Nsrc=FF_; Nalloc=320; Kp=KP_;  out = WT + lb + 242688; break;
      default:in = W2 + (size_t)d*FF_*K_; Kd=FF_; Nsrc=K_;  Nalloc=96;  Kp=FFP_; out = WT + lb + 273408; break;
    }
    int tiles_k = Kp / 32;
    int tiles_n = (Nalloc + 63) / 64;
    if (tile >= tiles_k * tiles_n) return;
    int tn = tile / tiles_k, tk = tile % tiles_k;
    int n0 = tn * 64, k0 = tk * 32;
    for (int i = threadIdx.x; i < 2048; i += 256) {
      int kk = i >> 6, nn = i & 63;
      int gk = k0 + kk, gn = n0 + nn;
      int srccol = gn;
      if (wt < 3) {
        int hh8 = gn / 80, ft = gn - hh8 * 80;
        srccol = (ft < 76) ? (hh8 * 76 + ft) : -1;
      }
      Ls[kk][nn] = (gk < Kd && srccol >= 0 && srccol < Nsrc) ? in[(size_t)gk * Nsrc + srccol] : 0.f;
    }
    __syncthreads();
    for (int i = threadIdx.x; i < 2048; i += 256) {
      int nn = i >> 5, kk = i & 31;
      int gn = n0 + nn;
      if (gn < Nalloc) out[(size_t)gn * Kp + k0 + kk] = f2b(Ls[kk][nn]);
    }
  } else if (bid < 1488) {
    int idx = (bid - 1368) * 256 + threadIdx.x;
    if (idx >= 96 * EK_) return;
    int n = idx / EK_, kk = idx % EK_;
    float val = 0.f;
    if (n < 76) {
      if (kk < 6) { if (n < 6) val = W_hp[kk * 6 + n]; }
      else if (kk < 143) { int i = kk - 6; if (n >= 6 && n < 36) val = W_lm[i * 30 + (n - 6)]; }
      else if (kk < 256) { int i = kk - 143; if (n >= 36 && n < 66) val = W_el[i * 30 + (n - 36)]; }
      else if (kk < 291) { int i = kk - 256; if (n >= 66) val = W_au[i * 10 + (n - 66)]; }
      else if (kk == 291) {
        val = (n < 6) ? b_hp[n] : (n < 36) ? b_lm[n - 6] : (n < 66) ? b_el[n - 36] : b_au[n - 66];
      }
    }
    WE[idx] = f2b(val);
  } else {
    int idx = (bid - 1488) * 256 + threadIdx.x;
    if (idx >= BT_ * (EK_ / 2)) return;
    int bt = idx / (EK_ / 2), dc = idx % (EK_ / 2);
    int c0 = dc * 2;
    auto fetch = [&](int c) -> float {
      if (c < 6) return v[bt * 6 + c];
      if (c < 143) return x[bt * 137 + c - 6];
      if (c < 256) return y[bt * 113 + c - 143];
      if (c < 291) return z[bt * 35 + c - 256];
      if (c == 291) return 1.0f;
      return 0.f;
    };
    ((u32*)xin)[idx] = pack2(fetch(c0), fetch(c0 + 1));
  }
}

// =================== MFMA GEMM (LDS-staged B, prefetch) — embed + QKV ====
template<int RT, int CT, int KSTEPS, int RELU, int TPB>
__global__ __launch_bounds__(TPB) void gemm_kernel(
    const u16* __restrict__ A, int lda,
    const u16* __restrict__ Wt, int ldw, unsigned long long wstride,
    const float* __restrict__ bias,
    u16* __restrict__ Cc, int ldc, int N,
    int ksplit, int klen, unsigned long long osplit,
    float cs,
    u16* __restrict__ vbt,
    const float* __restrict__ pos) {
  __shared__ u16 Bs[CT * 16 * 56];
  const int tid = threadIdx.x;
  const int w = tid >> 6, lane = tid & 63;
  const int r = lane & 15, g = lane >> 4;
  const int n0 = blockIdx.x * CT * 16;
  const int m0 = blockIdx.y * (TPB / 64) * 16 * RT;
  const int z = blockIdx.z;
  const int k0 = z * ksplit;
  const int kend = k0 + klen;
  const u16* Wz = Wt + (size_t)z * wstride;
  const float* bias_eff = (z == 0) ? bias : nullptr;
  const float csz = (z == 0) ? cs : 1.f;
  u16* Cz = Cc + (size_t)z * osplit;
  constexpr int NB = (CT * 64 + TPB - 1) / TPB;

  const f32x4 fz = {0.f, 0.f, 0.f, 0.f};
  f32x4 acc[RT][CT];
  #pragma unroll
  for (int rt = 0; rt < RT; rt++)
    #pragma unroll
    for (int ct = 0; ct < CT; ct++) acc[rt][ct] = fz;

  bf16x8 a_all[RT][KSTEPS];
  #pragma unroll
  for (int rt = 0; rt < RT; rt++) {
    const u16* arow = A + (size_t)(m0 + (w * RT + rt) * 16 + r) * lda;
    #pragma unroll
    for (int ks = 0; ks < KSTEPS; ks++) {
      int kA = k0 + ks * 32 + g * 8;
      if (kA < kend) a_all[rt][ks] = *(const bf16x8*)(arow + kA);
      else a_all[rt][ks] = bf16x8{0, 0, 0, 0, 0, 0, 0, 0};
    }
  }

  uint4 bpre[NB];
  auto loadB = [&](int ks) {
    int kk = k0 + ks * 32;
    #pragma unroll
    for (int i0 = 0; i0 < NB; i0++) {
      int idx = tid + i0 * TPB;
      bpre[i0] = make_uint4(0, 0, 0, 0);
      if (idx < CT * 64) {
        int nn = idx >> 2, kc = idx & 3;
        if (kk + kc * 8 < kend)
          bpre[i0] = *(const uint4*)(Wz + (size_t)(n0 + nn) * ldw + kk + kc * 8);
      }
    }
  };
  loadB(0);

  for (int ks = 0; ks < KSTEPS; ks++) {
    __syncthreads();
    #pragma unroll
    for (int i0 = 0; i0 < NB; i0++) {
      int idx = tid + i0 * TPB;
      if (idx < CT * 64) {
        int nn = idx >> 2, kc = idx & 3;
        *(uint4*)&Bs[nn * 56 + (((kc ^ (nn & 3)) << 3))] = bpre[i0];
      }
    }
    __syncthreads();
    if (ks + 1 < KSTEPS) loadB(ks + 1);
    #pragma unroll
    for (int ct = 0; ct < CT; ct++) {
      bf16x8 bb = *(const bf16x8*)&Bs[(ct * 16 + r) * 56 + (((g ^ (r & 3)) << 3))];
      #pragma unroll
      for (int rt = 0; rt < RT; rt++)
        acc[rt][ct] = __builtin_amdgcn_mfma_f32_16x16x32_bf16(a_all[rt][ks], bb, acc[rt][ct], 0, 0, 0);
    }
  }

  if (vbt && z == 2) {
    #pragma unroll
    for (int rt = 0; rt < RT; rt++) {
      #pragma unroll
      for (int ct = 0; ct < CT; ct++) {
        int feat = ct * 16 + r;
        int token = m0 + (w * RT + rt) * 16 + g * 4;
        int bb_ = token >> 10, tt = token & 1023;
        ushort4 pk;
        if (feat < 76) {
          pk.x = f2b(acc[rt][ct][0]); pk.y = f2b(acc[rt][ct][1]);
          pk.z = f2b(acc[rt][ct][2]); pk.w = f2b(acc[rt][ct][3]);
        } else {
          pk = make_ushort4(0, 0, 0, 0);
        }
        *(ushort4*)(vbt + (((size_t)(bb_ * 8 + blockIdx.x) * 80 + feat) << 10) + tt) = pk;
      }
    }
  } else {
    #pragma unroll
    for (int rt = 0; rt < RT; rt++) {
      #pragma unroll
      for (int ct = 0; ct < CT; ct++) {
        int col = n0 + ct * 16 + r;
        if (col < ldc) {
          #pragma unroll
          for (int reg = 0; reg < 4; reg++) {
            int row = m0 + (w * RT + rt) * 16 + g * 4 + reg;
            float val = acc[rt][ct][reg] * csz;
            if (bias_eff && col < N) val += bias_eff[col];
            if (pos && col < N) val += pos[(row & (T_ - 1)) * K_ + col];
            if (RELU) val = fmaxf(val, 0.f);
            Cz[(size_t)row * ldc + col] = f2b(val);
          }
        }
      }
    }
  }
}

// =================== fused FFN: Wu+LN1 -> W1+relu -> W2+LN2 (+optional out proj) ======
__global__ __launch_bounds__(64) void ffn_kernel(
    const u16* __restrict__ att, const u16* __restrict__ WuT, const float* __restrict__ bu,
    const u16* __restrict__ hres, const float* __restrict__ l1s, const float* __restrict__ l1b,
    const u16* __restrict__ W1T, const float* __restrict__ b1,
    const u16* __restrict__ W2T, const float* __restrict__ b2,
    const float* __restrict__ l2s, const float* __restrict__ l2b,
    u16* __restrict__ hout,
    const float* __restrict__ Wout, const float* __restrict__ bout,
    float* __restrict__ outp) {
  __shared__ u16 Bs[6 * 16 * 56];
  __shared__ u16 h1s[16 * 104];
  __shared__ u16 ffs[16 * 328];
  const int lane = threadIdx.x & 63;
  const int r = lane & 15, g = lane >> 4;
  const int m0 = blockIdx.x * 16;
  const f32x4 fz = {0.f, 0.f, 0.f, 0.f};

  u16 resv[4][6];
  #pragma unroll
  for (int reg = 0; reg < 4; reg++)
    #pragma unroll
    for (int ct = 0; ct < 6; ct++)
      resv[reg][ct] = hres[(size_t)(m0 + g * 4 + reg) * KP_ + ct * 16 + r];

  // ---- stage 1: u = att @ WuT ----
  bf16x8 a1[19];
  {
    const u16* arow = att + (size_t)(m0 + r) * HK_;
    #pragma unroll
    for (int ks = 0; ks < 19; ks++) a1[ks] = *(const bf16x8*)(arow + ks * 32 + g * 8);
  }
  f32x4 acc1[6];
  #pragma unroll
  for (int ct = 0; ct < 6; ct++) acc1[ct] = fz;
  {
    uint4 bpre[6];
    auto loadB1 = [&](int ks) {
      #pragma unroll
      for (int i0 = 0; i0 < 6; i0++) {
        int idx = lane + i0 * 64;
        int nn = idx >> 2, kc = idx & 3;
        bpre[i0] = *(const uint4*)(WuT + (size_t)nn * HK_ + ks * 32 + kc * 8);
      }
    };
    loadB1(0);
    for (int ks = 0; ks < 19; ks++) {
      #pragma unroll
      for (int i0 = 0; i0 < 6; i0++) {
        int idx = lane + i0 * 64;
        int nn = idx >> 2, kc = idx & 3;
        *(uint4*)&Bs[nn * 56 + ((kc ^ (nn & 3)) << 3)] = bpre[i0];
      }
      if (ks + 1 < 19) loadB1(ks + 1);
      #pragma unroll
      for (int ct = 0; ct < 6; ct++) {
        bf16x8 bb = *(const bf16x8*)&Bs[(ct * 16 + r) * 56 + ((g ^ (r & 3)) << 3)];
        acc1[ct] = __builtin_amdgcn_mfma_f32_16x16x32_bf16(a1[ks], bb, acc1[ct], 0, 0, 0);
      }
    }
  }
  #pragma unroll
  for (int reg = 0; reg < 4; reg++) {
    float vals[6];
    float s = 0.f, s2 = 0.f;
    #pragma unroll
    for (int ct = 0; ct < 6; ct++) {
      int col = ct * 16 + r;
      float val = 0.f;
      if (col < K_) {
        val = acc1[ct][reg] + bu[col] + b2f(resv[reg][ct]);
        s += val; s2 += val * val;
      }
      vals[ct] = val;
    }
    #pragma unroll
    for (int m = 1; m < 16; m <<= 1) { s += __shfl_xor(s, m); s2 += __shfl_xor(s2, m); }
    float mu = s * (1.f / 76.f);
    float rstd = rsqrtf(s2 * (1.f / 76.f) - mu * mu + EPS_);
    #pragma unroll
    for (int ct = 0; ct < 6; ct++) {
      int col = ct * 16 + r;
      u16 ov = 0;
      if (col < K_) ov = f2b((vals[ct] - mu) * rstd * l1s[col] + l1b[col]);
      h1s[(g * 4 + reg) * 104 + col] = ov;
    }
  }

  // ---- stage 2: ff = relu(h1 @ W1T + b1) ----
  bf16x8 a2[3];
  #pragma unroll
  for (int ks = 0; ks < 3; ks++)
    a2[ks] = *(const bf16x8*)&h1s[r * 104 + ks * 32 + g * 8];
  f32x4 acc2[20];
  #pragma unroll
  for (int ct = 0; ct < 20; ct++) acc2[ct] = fz;
  #pragma unroll
  for (int ks = 0; ks < 3; ks++) {
    bf16x8 bb[20];
    #pragma unroll
    for (int ct = 0; ct < 20; ct++)
      bb[ct] = *(const bf16x8*)(W1T + (size_t)(ct * 16 + r) * KP_ + ks * 32 + g * 8);
    #pragma unroll
    for (int ct = 0; ct < 20; ct++)
      acc2[ct] = __builtin_amdgcn_mfma_f32_16x16x32_bf16(a2[ks], bb[ct], acc2[ct], 0, 0, 0);
  }
  #pragma unroll
  for (int reg = 0; reg < 4; reg++)
    #pragma unroll
    for (int ct = 0; ct < 20; ct++) {
      int col = ct * 16 + r;
      float val = acc2[ct][reg] + ((col < FF_) ? b1[col] : 0.f);
      ffs[(g * 4 + reg) * 328 + col] = f2b(fmaxf(val, 0.f));
    }

  // ---- stage 3: u2 = ff @ W2T + b2 + h1 residual + LN2 (+out proj) ----
  bf16x8 a3[10];
  #pragma unroll
  for (int ks = 0; ks < 10; ks++)
    a3[ks] = *(const bf16x8*)&ffs[r * 328 + ks * 32 + g * 8];
  f32x4 acc3[6];
  #pragma unroll
  for (int ct = 0; ct < 6; ct++) acc3[ct] = fz;
  {
    uint4 bpre[6];
    auto loadB3 = [&](int ks) {
      #pragma unroll
      for (int i0 = 0; i0 < 6; i0++) {
        int idx = lane + i0 * 64;
        int nn = idx >> 2, kc = idx & 3;
        bpre[i0] = *(const uint4*)(W2T + (size_t)nn * FFP_ + ks * 32 + kc * 8);
      }
    };
    loadB3(0);
    for (int ks = 0; ks < 10; ks++) {
      #pragma unroll
      for (int i0 = 0; i0 < 6; i0++) {
        int idx = lane + i0 * 64;
        int nn = idx >> 2, kc = idx & 3;
        *(uint4*)&Bs[nn * 56 + ((kc ^ (nn & 3)) << 3)] = bpre[i0];
      }
      if (ks + 1 < 10) loadB3(ks + 1);
      #pragma unroll
      for (int ct = 0; ct < 6; ct++) {
        bf16x8 bb = *(const bf16x8*)&Bs[(ct * 16 + r) * 56 + ((g ^ (r & 3)) << 3)];
        acc3[ct] = __builtin_amdgcn_mfma_f32_16x16x32_bf16(a3[ks], bb, acc3[ct], 0, 0, 0);
      }
    }
  }
  #pragma unroll
  for (int reg = 0; reg < 4; reg++) {
    float vals[6];
    float s = 0.f, s2 = 0.f;
    #pragma unroll
    for (int ct = 0; ct < 6; ct++) {
      int col = ct * 16 + r;
      float val = 0.f;
      if (col < K_) {
        val = acc3[ct][reg] + b2[col] + b2f(h1s[(g * 4 + reg) * 104 + col]);
        s += val; s2 += val * val;
      }
      vals[ct] = val;
    }
    #pragma unroll
    for (int m = 1; m < 16; m <<= 1) { s += __shfl_xor(s, m); s2 += __shfl_xor(s2, m); }
    float mu = s * (1.f / 76.f);
    float rstd = rsqrtf(s2 * (1.f / 76.f) - mu * mu + EPS_);
    u16* outr = hout + (size_t)(m0 + g * 4 + reg) * KP_;
    float p0 = 0.f, p1 = 0.f;
    #pragma unroll
    for (int ct = 0; ct < 6; ct++) {
      int col = ct * 16 + r;
      u16 ov = 0;
      if (col < K_) {
        float vln = (vals[ct] - mu) * rstd * l2s[col] + l2b[col];
        ov = f2b(vln);
        if (outp) {
          p0 += vln * Wout[col * 2];
          p1 += vln * Wout[col * 2 + 1];
        }
      }
      outr[col] = ov;
    }
    if (outp) {
      #pragma unroll
      for (int m = 1; m < 16; m <<= 1) { p0 += __shfl_xor(p0, m); p1 += __shfl_xor(p1, m); }
      if (r == 0) {
        int row = m0 + g * 4 + reg;
        outp[row * 2] = p0 + bout[0];
        outp[row * 2 + 1] = p1 + bout[1];
      }
    }
  }
}

// =================== flash attention: 4-wave rt=2, single-buffered K/V (proven) ===
__global__ __launch_bounds__(256, 3) void attn_kernel(const u16* __restrict__ q,
                                                      const u16* __restrict__ k,
                                                      const u16* __restrict__ vbt,
                                                      u16* __restrict__ att) {
  __shared__ u16 Ks[64 * 104];   // 52 dw stride (13 odd -> conflict-free b128)
  __shared__ u16 Vs[80 * 72];    // 36 dw stride (9 odd)
  __shared__ u32 Psw[128 * 36];  // wave-private rows
  const int bid = blockIdx.x;
  const int hh = bid & 7, b = (bid >> 3) & 7, qt = bid >> 6;
  const int tid = threadIdx.x;
  const int w = tid >> 6, lane = tid & 63;
  const int r = lane & 15, g = lane >> 4;
  const int qbase = b * T_ + qt * 128;

  bf16x8 aq[2][3];
  #pragma unroll
  for (int rt = 0; rt < 2; rt++) {
    const u16* qsrc = q + (size_t)(qbase + w * 32 + rt * 16 + r) * QKLD_ + hh * 80;
    #pragma unroll
    for (int ks = 0; ks < 3; ks++) {
      int e0 = ks * 32 + g * 8;
      aq[rt][ks] = (e0 < 80) ? *(const bf16x8*)(qsrc + e0) : bf16x8{0, 0, 0, 0, 0, 0, 0, 0};
    }
  }

  const int krow = tid >> 2, kq4 = tid & 3;
  uint4 kpre[3], vpre[3];
  auto stage_load = [&](int kt) {
    const int kb = b * T_ + kt * 64;
    const u16* ksrc = k + (size_t)(kb + krow) * QKLD_ + hh * 80;
    #pragma unroll
    for (int i = 0; i < 3; i++) {
      int c = kq4 + 4 * i;
      kpre[i] = (c < 10) ? *(const uint4*)(ksrc + c * 8) : make_uint4(0, 0, 0, 0);
    }
    const u16* vsrc = vbt + (((size_t)(b * 8 + hh) * 80) << 10) + kt * 64;
    #pragma unroll
    for (int p = 0; p < 3; p++) {
      int idx = tid + p * 256;
      vpre[p] = (idx < 640) ? *(const uint4*)(vsrc + ((size_t)(idx >> 3) << 10) + (idx & 7) * 8)
                            : make_uint4(0, 0, 0, 0);
    }
  };
  auto stage_write = [&]() {
    #pragma unroll
    for (int i = 0; i < 3; i++) {
      int c = kq4 + 4 * i;
      *(uint4*)&Ks[krow * 104 + c * 8] = kpre[i];
    }
    #pragma unroll
    for (int p = 0; p < 3; p++) {
      int idx = tid + p * 256;
      if (idx < 640)
        *(uint4*)&Vs[(idx >> 3) * 72 + (idx & 7) * 8] = vpre[p];
    }
  };

  u32* Pw = Psw + w * 32 * 36;

  const f32x4 fz = {0.f, 0.f, 0.f, 0.f};
  f32x4 o[2][5];
  float ls[2] = {0.f, 0.f};
  #pragma unroll
  for (int rt = 0; rt < 2; rt++)
    #pragma unroll
    for (int i = 0; i < 5; i++) o[rt][i] = fz;

  stage_load(0);

  for (int kt = 0; kt < 16; kt++) {
    __syncthreads();
    stage_write();
    __syncthreads();
    if (kt < 15) stage_load(kt + 1);

    f32x4 st[2][4];
    #pragma unroll
    for (int ct = 0; ct < 4; ct++) { st[0][ct] = fz; st[1][ct] = fz; }
    __builtin_amdgcn_s_setprio(1);
    #pragma unroll
    for (int ct = 0; ct < 4; ct++) {
      #pragma unroll
      for (int ks = 0; ks < 3; ks++) {
        bf16x8 ak = *(const bf16x8*)&Ks[(ct * 16 + r) * 104 + ks * 32 + g * 8];
        st[0][ct] = __builtin_amdgcn_mfma_f32_16x16x32_bf16(ak, aq[0][ks], st[0][ct], 0, 0, 0);
        st[1][ct] = __builtin_amdgcn_mfma_f32_16x16x32_bf16(ak, aq[1][ks], st[1][ct], 0, 0, 0);
      }
    }
    __builtin_amdgcn_s_setprio(0);

    #pragma unroll
    for (int rt = 0; rt < 2; rt++) {
      float rs = 0.f;
      u32 pk[8];
      #pragma unroll
      for (int ct = 0; ct < 4; ct++) {
        float p0 = exp2f(st[rt][ct][0]), p1 = exp2f(st[rt][ct][1]);
        float p2 = exp2f(st[rt][ct][2]), p3 = exp2f(st[rt][ct][3]);
        rs += (p0 + p1) + (p2 + p3);
        pk[ct * 2] = pack2(p0, p1);
        pk[ct * 2 + 1] = pack2(p2, p3);
      }
      ls[rt] += rs;
      u32* pw = Pw + (rt * 16 + r) * 36;
      #pragma unroll
      for (int ct = 0; ct < 4; ct++)
        *(uint2*)(pw + ct * 8 + g * 2) = make_uint2(pk[ct * 2], pk[ct * 2 + 1]);
    }

    bf16x8 pa[2][2];
    #pragma unroll
    for (int rt = 0; rt < 2; rt++) {
      const u32* pr = Pw + (rt * 16 + r) * 36;
      #pragma unroll
      for (int ks = 0; ks < 2; ks++) {
        uint4 t = *(const uint4*)(pr + ks * 16 + g * 4);
        pa[rt][ks] = *reinterpret_cast<bf16x8*>(&t);
      }
    }
    __builtin_amdgcn_s_setprio(1);
    #pragma unroll
    for (int ks = 0; ks < 2; ks++) {
      #pragma unroll
      for (int c5 = 0; c5 < 5; c5++) {
        bf16x8 av = *(const bf16x8*)&Vs[(c5 * 16 + r) * 72 + ks * 32 + g * 8];
        #pragma unroll
        for (int rt = 0; rt < 2; rt++)
          o[rt][c5] = __builtin_amdgcn_mfma_f32_16x16x32_bf16(av, pa[rt][ks], o[rt][c5], 0, 0, 0);
      }
    }
    __builtin_amdgcn_s_setprio(0);
  }

  #pragma unroll
  for (int rt = 0; rt < 2; rt++) {
    ls[rt] += __shfl_xor(ls[rt], 16);
    ls[rt] += __shfl_xor(ls[rt], 32);
    float inv = 1.f / ls[rt];
    int token = qbase + w * 32 + rt * 16 + r;
    #pragma unroll
    for (int c5 = 0; c5 < 5; c5++) {
      if (c5 == 4 && g == 3) continue;
      ushort4 pk4;
      pk4.x = f2b(o[rt][c5][0] * inv);
      pk4.y = f2b(o[rt][c5][1] * inv);
      pk4.z = f2b(o[rt][c5][2] * inv);
      pk4.w = f2b(o[rt][c5][3] * inv);
      *(ushort4*)&att[(size_t)token * HK_ + hh * 76 + c5 * 16 + g * 4] = pk4;
    }
  }
}

extern "C" void kernel_launch(void* const* d_in, const int* in_sizes, int n_in,
                              void* d_out, int out_size, void* d_ws, size_t ws_size,
                              hipStream_t stream) {
  const float* v    = (const float*)d_in[0];
  const float* x    = (const float*)d_in[1];
  const float* y    = (const float*)d_in[2];
  const float* z    = (const float*)d_in[3];
  const float* W_hp = (const float*)d_in[4];
  const float* b_hp = (const float*)d_in[5];
  const float* W_lm = (const float*)d_in[6];
  const float* b_lm = (const float*)d_in[7];
  const float* W_el = (const float*)d_in[8];
  const float* b_el = (const float*)d_in[9];
  const float* W_au = (const float*)d_in[10];
  const float* b_au = (const float*)d_in[11];
  const float* pos  = (const float*)d_in[12];
  const float* Wq   = (const float*)d_in[13];
  const float* Wk   = (const float*)d_in[14];
  const float* Wv   = (const float*)d_in[15];
  const float* Wu   = (const float*)d_in[16];
  const float* bu   = (const float*)d_in[17];
  const float* ln1s = (const float*)d_in[18];
  const float* ln1b = (const float*)d_in[19];
  const float* W1   = (const float*)d_in[20];
  const float* b1   = (const float*)d_in[21];
  const float* W2   = (const float*)d_in[22];
  const float* b2   = (const float*)d_in[23];
  const float* ln2s = (const float*)d_in[24];
  const float* ln2b = (const float*)d_in[25];
  const float* Wout = (const float*)d_in[26];
  const float* bout = (const float*)d_in[27];

  u16* ws  = (u16*)d_ws;
  u16* WT  = ws;                          // 6*304128 = 1824768
  u16* WE  = WT + 1824768;                // 96*320
  u16* h   = WE + 30720;                  // 8192*96
  u16* xin = h + 786432;                  // 8192*320
  u16* qb  = xin + 2621440;               // 8192*640
  u16* kb  = qb + 5242880;                // 8192*640
  u16* vbt = kb + 5242880;                // 64*80*1024
  u16* att = vbt + 5242880;               // 8192*608

  prep_kernel<<<dim3(6608), 256, 0, stream>>>(
      Wq, Wk, Wv, Wu, W1, W2, WT,
      W_hp, b_hp, W_lm, b_lm, W_el, b_el, W_au, b_au, WE,
      v, x, y, z, xin);
  // embed GEMM: h = xin @ WE^T (+pos epilogue)
  gemm_kernel<1, 6, 10, 0, 128><<<dim3(1, 256, 1), 128, 0, stream>>>(
      xin, EK_, WE, EK_, 0ULL, nullptr, h, KP_, K_, 0, EK_, 0ULL,
      1.f, nullptr, pos);

  for (int d = 0; d < D_; d++) {
    u16* WTd = WT + (size_t)d * PER_L_;
    const float* bu_d = bu + (size_t)d * K_;
    const float* l1s  = ln1s + (size_t)d * K_;
    const float* l1b  = ln1b + (size_t)d * K_;
    const float* b1_d = b1 + (size_t)d * FF_;
    const float* b2_d = b2 + (size_t)d * K_;
    const float* l2s  = ln2s + (size_t)d * K_;
    const float* l2b  = ln2b + (size_t)d * K_;

    // QKV: z=0 -> qb (scaled by SCL2_), z=1 -> kb, z=2 -> vbt (transposed)
    gemm_kernel<2, 5, 3, 0, 256><<<dim3(8, 64, 3), 256, 0, stream>>>(
        h, KP_, WTd, KP_, 61440ULL, nullptr, qb, QKLD_, QKLD_, 0, KP_, 5242880ULL,
        SCL2_, vbt, nullptr);
    attn_kernel<<<dim3(512), 256, 0, stream>>>(qb, kb, vbt, att);
    // fused FFN (+ final out projection on the last layer)
    ffn_kernel<<<dim3(512), 64, 0, stream>>>(
        att, WTd + 184320, bu_d, h, l1s, l1b,
        WTd + 242688, b1_d, WTd + 273408, b2_d, l2s, l2b, h,
        Wout, bout, (d == D_ - 1) ? (float*)d_out : nullptr);
  }
}